// Round 17
// baseline (298.844 us; speedup 1.0000x reference)
//
#include <hip/hip_runtime.h>

typedef __attribute__((ext_vector_type(8))) short bf16x8;
typedef __attribute__((ext_vector_type(4))) float f32x4;
typedef __attribute__((ext_vector_type(8))) unsigned short u16x8;

#define DEVINL __device__ __forceinline__
#define AS1 __attribute__((address_space(1)))
#define AS3 __attribute__((address_space(3)))

constexpr int NI = 256;   // input channels (K)
constexpr int NO = 256;   // output channels
constexpr int NC = 120;   // irrep feature width
constexpr int BROW = NC * NI;                        // 30720 f32 per b of x
constexpr int CPLANE = 1024 * NI;                    // 262144: one c-plane of xt
constexpr int WELEMS = 56 * NO * NI;                 // 3,670,016
constexpr size_t XT_ELEMS = (size_t)NC * 1024 * NI;  // 31,457,280

DEVINL ushort f2bf(float x) {   // round-to-nearest-even fp32 -> bf16 bits
  unsigned u = __float_as_uint(x);
  u += 0x7FFFu + ((u >> 16) & 1u);
  return (ushort)(u >> 16);
}
DEVINL float bf2f(ushort v) { return __uint_as_float((unsigned)v << 16); }

// ---- prep: wb[((m*32 + k/8)*256 + o)*8 + k%8] = bf16(W_m[o][k]) ----
__global__ __launch_bounds__(256) void prep_w(const float* __restrict__ w0,
                                              const float* __restrict__ w1,
                                              const float* __restrict__ w2,
                                              ushort* __restrict__ wb) {
  const int m = blockIdx.x >> 5;        // 0..55
  const int kc = blockIdx.x & 31;       // k-chunk of 8
  const int o = threadIdx.x;            // 0..255
  const float* src;
  if (m < 32)      src = w0 + ((size_t)(m * NO + o)) * NI;
  else if (m < 48) src = w1 + ((size_t)((m - 32) * NO + o)) * NI;
  else             src = w2 + ((size_t)((m - 48) * NO + o)) * NI;
  src += kc * 8;
  float4 a = *reinterpret_cast<const float4*>(src);
  float4 b = *reinterpret_cast<const float4*>(src + 4);
  u16x8 p = { f2bf(a.x), f2bf(a.y), f2bf(a.z), f2bf(a.w),
              f2bf(b.x), f2bf(b.y), f2bf(b.z), f2bf(b.w) };
  *reinterpret_cast<u16x8*>(wb + ((size_t)(blockIdx.x * 256 + o)) * 8) = p;
}

// ---- pass 1 v5: x [1024 b][256 i][120 c] f32 -> TILED xt bf16:
// element (c,b,k) at c*CPLANE + (b>>5)*8192 + (k>>6)*2048 + (b&31)*64 + (k&63)
// (4 KB GEMM stage tiles are contiguous). Same LDS scheme as proven v4; since
// this block's k-range is iq*64..+64, S = iq exactly -> dst formula only change.
__global__ __launch_bounds__(256) void xpose(const float* __restrict__ x,
                                             ushort* __restrict__ xt) {
  __shared__ float tl[64 * 121];       // 31 KB -> 5 blocks/CU
  const int bid = blockIdx.x;          // 4096 = b*4 + iq
  const int b = bid >> 2, iq = bid & 3;
  const int t = threadIdx.x;
  const float* xb = x + (size_t)b * BROW + (size_t)iq * 64 * NC;
#pragma unroll
  for (int j = 0; j < 15; ++j) {       // 7680 f32, float2 coalesced reads
    const int e = (j * 256 + t) * 2;   // even -> c even, no row wrap (c<=118)
    float2 v = *reinterpret_cast<const float2*>(xb + e);
    const int i = e / 120, c = e % 120;
    tl[i * 121 + c] = v.x;
    tl[i * 121 + c + 1] = v.y;
  }
  __syncthreads();
  ushort* dst = xt + (size_t)(b >> 5) * 8192 + (size_t)iq * 2048 + (b & 31) * 64;
#pragma unroll
  for (int q = 0; q < 4; ++q) {        // 960 chunks (120 c x 8 ich), predicated
    const int chunk = q * 256 + t;
    if (chunk < 960) {
      const int c = chunk >> 3, ich = chunk & 7;
      u16x8 p;
#pragma unroll
      for (int k = 0; k < 8; ++k) p[k] = f2bf(tl[(ich * 8 + k) * 121 + c]);
      *reinterpret_cast<u16x8*>(dst + (size_t)c * CPLANE + ich * 8) = p;
    }
  }
}

// ---- pass 2 (FUSED, final): block = 8c x 64b x 64o, 8 waves. Wave w owns
// c = c0+w (ONE runtime wave-uniform matrix). K=256 as 2 b-halves x 4 K-stages
// of 64 (stage tile [32 b][64 k]/plane, 128B rows -> e3mix6-proven conflict-free
// involution). W:out amortized 0.5 loads:MFMA; W L2-resident (ct slowest).
// Epilogue: R13-proven [32][520] repack x2 halves -> 32B f32 runs (no otrans).
__global__ __launch_bounds__(512, 4) void e3mixC(const ushort* __restrict__ xt,
                                                 const ushort* __restrict__ wb,
                                                 const float* __restrict__ bias0,
                                                 float* __restrict__ out) {
  __shared__ ushort xs[32768];         // 64 KB: staging dbuf 2x32KB; epilogue reuse
  const int bid = blockIdx.x;          // 960 = ct*64 + bt*4 + oq
  const int ct = bid >> 6;             // 0..14, SLOWEST -> W set L2-resident
  const int bt = (bid >> 2) & 15;
  const int oq = bid & 3;              // xt slice re-reads ride L3 (63 MB resident)
  const int c0 = ct * 8, bg = bt * 64, og = oq * 64;

  const int tid = threadIdx.x, lane = tid & 63, w = tid >> 6;   // 8 waves
  const int rb = lane & 15, rg = lane >> 4;
  const int c = c0 + w;                // wave's column; all 120 covered, no tail
  const int m = c < 32 ? c : (c < 80 ? 32 + (c - 32) / 3 : 48 + (c - 80) / 5);

  // staging source: instr j covers rows r = j*8 + lr; kc = (lane&7)^lr is
  // j/bh/s-invariant ((j*8+lr)&7 == lr). LDS dest linear (HW rule).
  const int lr = lane >> 3;
  const ushort* gbase = xt + (size_t)c * CPLANE + (size_t)bt * 16384
                           + lr * 64 + ((lane & 7) ^ lr) * 8;

  f32x4 acc[4][4];                     // [bh*2+fb][fo]
#pragma unroll
  for (int i = 0; i < 4; ++i)
#pragma unroll
    for (int j = 0; j < 4; ++j) acc[i][j] = (f32x4)0.0f;

#define STAGEC(BUF, G)                                                         \
  do {                                                                         \
    const ushort* gs_ = gbase + ((G) >> 2) * 8192 + ((G) & 3) * 2048;          \
    ushort* ld_ = xs + (BUF) * 16384 + w * 2048;                               \
    __builtin_amdgcn_global_load_lds((const AS1 void*)(gs_),        (AS3 void*)(ld_),        16, 0, 0); \
    __builtin_amdgcn_global_load_lds((const AS1 void*)(gs_ + 512),  (AS3 void*)(ld_ + 512),  16, 0, 0); \
    __builtin_amdgcn_global_load_lds((const AS1 void*)(gs_ + 1024), (AS3 void*)(ld_ + 1024), 16, 0, 0); \
    __builtin_amdgcn_global_load_lds((const AS1 void*)(gs_ + 1536), (AS3 void*)(ld_ + 1536), 16, 0, 0); \
  } while (0)

  STAGEC(0, 0);
  __syncthreads();                     // phase 0 staged

#pragma unroll
  for (int g = 0; g < 8; ++g) {        // full unroll: acc indices static
    if (g < 7) STAGEC((g + 1) & 1, g + 1);      // prefetch next phase
    const int bh = g >> 2, s = g & 3;
    const ushort* p = xs + (g & 1) * 16384 + w * 2048;   // wave's [32 b][64 k]
#pragma unroll
    for (int kh = 0; kh < 2; ++kh) {   // two k-halves of 32
      bf16x8 a[2], wf[4];
#pragma unroll
      for (int fb = 0; fb < 2; ++fb)   // A frags: proven swizzle, conflict-free
        a[fb] = *reinterpret_cast<const bf16x8*>(
            p + (fb * 16 + rb) * 64 + (((kh * 4 + rg) ^ (rb & 7)) * 8));
#pragma unroll
      for (int fo = 0; fo < 4; ++fo)   // W frags: 256B-coalesced, L2-hot
        wf[fo] = *reinterpret_cast<const bf16x8*>(
            wb + ((size_t)((m * 32 + s * 8 + kh * 4 + rg) * NO
                           + og + fo * 16 + rb)) * 8);
#pragma unroll
      for (int fb = 0; fb < 2; ++fb)
#pragma unroll
        for (int fo = 0; fo < 4; ++fo)
          acc[bh * 2 + fb][fo] = __builtin_amdgcn_mfma_f32_16x16x32_bf16(
              a[fb], wf[fo], acc[bh * 2 + fb][fo], 0, 0, 0);
    }
    __syncthreads();                   // drains prefetch; protects buf reuse
  }
#undef STAGEC

  if (ct < 4) {                        // c0 < 32: l=0 irreps carry bias b0[c][o]
#pragma unroll
    for (int fo = 0; fo < 4; ++fo) {
      const float bv = bias0[c * NO + og + fo * 16 + rb];
#pragma unroll
      for (int i = 0; i < 4; ++i) acc[i][fo] += bv;
    }
  }

  // epilogue: per b-half, repack [32 b'][64 o][8 c] bf16 (stride 520,
  // R13-proven banks) -> 32B-contiguous f32 stores.
#pragma unroll 1
  for (int h = 0; h < 2; ++h) {
    if (h) __syncthreads();            // previous half's reads done
#pragma unroll
    for (int fb = 0; fb < 2; ++fb)
#pragma unroll
      for (int r = 0; r < 4; ++r)
#pragma unroll
        for (int fo = 0; fo < 4; ++fo)
          xs[(fb * 16 + rg * 4 + r) * 520 + (fo * 16 + rb) * 8 + w] =
              f2bf(acc[h * 2 + fb][fo][r]);
    __syncthreads();
#pragma unroll
    for (int i = 0; i < 4; ++i) {      // 2048 (b,o) groups per half, 4/thread
      const int g = i * 512 + tid;
      const int bp = g >> 6, o = g & 63;
      u16x8 v = *reinterpret_cast<const u16x8*>(xs + bp * 520 + o * 8);
      float4 lo = make_float4(bf2f(v[0]), bf2f(v[1]), bf2f(v[2]), bf2f(v[3]));
      float4 hi = make_float4(bf2f(v[4]), bf2f(v[5]), bf2f(v[6]), bf2f(v[7]));
      float* dst = out + ((size_t)(bg + h * 32 + bp) * NO + og + o) * NC + c0;
      *reinterpret_cast<float4*>(dst) = lo;     // 32B contiguous, 32B-aligned
      *reinterpret_cast<float4*>(dst + 4) = hi;
    }
  }
}

// ---- fallback (small ws): direct strided gather from x, validated in R5 ----
__global__ __launch_bounds__(512, 4) void e3mix2f(const float* __restrict__ x,
                                                  const ushort* __restrict__ wb,
                                                  const float* __restrict__ bias0,
                                                  float* __restrict__ out) {
  __shared__ ushort xs[8 * 16 * 64];
  const int bid = blockIdx.x;          // 960 = 15 ct * 64 bt
  const int ct = bid % 15, bt = bid / 15;
  const int c0 = ct * 8, bg = bt * 16;
  const int t = threadIdx.x, lane = t & 63, wid = t >> 6;
  const int sb = lane >> 2, sp = lane & 3;
  const int rb = lane & 15, rg = lane >> 4;
  const int oc = wid * 16 + rb;
  const int srow = (wid * 16 + sb) * 64;
  const int sk0 = (sp * 16) ^ ((sb & 7) << 3);
  const int sk1 = (sp * 16 + 8) ^ ((sb & 7) << 3);

  f32x4 acc[8][2];
#pragma unroll
  for (int i = 0; i < 8; ++i) { acc[i][0] = (f32x4)0.0f; acc[i][1] = (f32x4)0.0f; }
  bf16x8 w00 = {}, w01 = {}, w10 = {}, w11 = {};

#pragma unroll 1
  for (int s = 0; s < 4; ++s) {
    if (s) __syncthreads();
    u16x8 v0, v1;
    const float* src = x + (size_t)(bg + sb) * (NI * NC)
                         + (size_t)(s * 64 + sp * 16) * NC + (c0 + wid);
#pragma unroll
    for (int jj = 0; jj < 8; ++jj) v0[jj] = f2bf(src[jj * NC]);
#pragma unroll
    for (int jj = 0; jj < 8; ++jj) v1[jj] = f2bf(src[(8 + jj) * NC]);
    *reinterpret_cast<u16x8*>(&xs[srow + sk0]) = v0;
    *reinterpret_cast<u16x8*>(&xs[srow + sk1]) = v1;
    __syncthreads();

    int mprev = -1;
#pragma unroll
    for (int cc = 0; cc < 8; ++cc) {
      const int c = c0 + cc;
      const int m = c < 32 ? c : (c < 80 ? 32 + (c - 32) / 3 : 48 + (c - 80) / 5);
      if (m != mprev) {
        const ushort* wp = wb + ((size_t)((m * 32 + s * 8 + rg) * NO + oc)) * 8;
        w00 = *reinterpret_cast<const bf16x8*>(wp);
        w10 = *reinterpret_cast<const bf16x8*>(wp + (size_t)4 * NO * 8);
        w01 = *reinterpret_cast<const bf16x8*>(wp + 128 * 8);
        w11 = *reinterpret_cast<const bf16x8*>(wp + (size_t)4 * NO * 8 + 128 * 8);
        mprev = m;
      }
      const ushort* xp = xs + (cc * 16 + rb) * 64;
      const int sz = (rb & 7) << 3;
      bf16x8 a0 = *reinterpret_cast<const bf16x8*>(xp + ((rg * 8) ^ sz));
      bf16x8 a1 = *reinterpret_cast<const bf16x8*>(xp + ((32 + rg * 8) ^ sz));
      acc[cc][0] = __builtin_amdgcn_mfma_f32_16x16x32_bf16(a0, w00, acc[cc][0], 0, 0, 0);
      acc[cc][0] = __builtin_amdgcn_mfma_f32_16x16x32_bf16(a1, w10, acc[cc][0], 0, 0, 0);
      acc[cc][1] = __builtin_amdgcn_mfma_f32_16x16x32_bf16(a0, w01, acc[cc][1], 0, 0, 0);
      acc[cc][1] = __builtin_amdgcn_mfma_f32_16x16x32_bf16(a1, w11, acc[cc][1], 0, 0, 0);
    }
  }

  if (c0 < 32) {
#pragma unroll
    for (int cc = 0; cc < 8; ++cc) {
      acc[cc][0] += bias0[(c0 + cc) * NO + oc];
      acc[cc][1] += bias0[(c0 + cc) * NO + oc + 128];
    }
  }

  const int br0 = bg + rg * 4;
#pragma unroll
  for (int of = 0; of < 2; ++of)
#pragma unroll
    for (int r = 0; r < 4; ++r) {
      float4 va = make_float4(acc[0][of][r], acc[1][of][r], acc[2][of][r], acc[3][of][r]);
      float4 vb = make_float4(acc[4][of][r], acc[5][of][r], acc[6][of][r], acc[7][of][r]);
      float* dst = out + ((size_t)(br0 + r) * NO + oc + of * 128) * NC + c0;
      *reinterpret_cast<float4*>(dst) = va;
      *reinterpret_cast<float4*>(dst + 4) = vb;
    }
}

extern "C" void kernel_launch(void* const* d_in, const int* in_sizes, int n_in,
                              void* d_out, int out_size, void* d_ws, size_t ws_size,
                              hipStream_t stream) {
  const float* x  = (const float*)d_in[0];
  const float* w0 = (const float*)d_in[1];
  const float* w1 = (const float*)d_in[2];
  const float* w2 = (const float*)d_in[3];
  const float* b0 = (const float*)d_in[4];
  float* out = (float*)d_out;
  ushort* wb = (ushort*)d_ws;                       // 7.34 MB
  ushort* xt = wb + WELEMS;                         // +62.9 MB (tiled)

  prep_w<<<56 * 32, 256, 0, stream>>>(w0, w1, w2, wb);
  const bool big = ws_size >= (size_t)2 * (WELEMS + XT_ELEMS);
  if (big) {
    xpose<<<4096, 256, 0, stream>>>(x, xt);
    e3mixC<<<960, 512, 0, stream>>>(xt, wb, b0, out);
  } else {
    e3mix2f<<<960, 512, 0, stream>>>(x, wb, b0, out);
  }
}

// Round 18
// 293.764 us; speedup vs baseline: 1.0173x; 1.0173x over previous
//
#include <hip/hip_runtime.h>

typedef __attribute__((ext_vector_type(8))) short bf16x8;
typedef __attribute__((ext_vector_type(4))) float f32x4;
typedef __attribute__((ext_vector_type(8))) unsigned short u16x8;

#define DEVINL __device__ __forceinline__
#define AS1 __attribute__((address_space(1)))
#define AS3 __attribute__((address_space(3)))

constexpr int NI = 256;   // input channels (K)
constexpr int NO = 256;   // output channels
constexpr int NC = 120;   // irrep feature width
constexpr int BROW = NC * NI;                        // 30720 f32 per b of x
constexpr int CPLANE = 1024 * NI;                    // 262144: one c-plane of xt
constexpr int WELEMS = 56 * NO * NI;                 // 3,670,016
constexpr size_t XT_ELEMS = (size_t)NC * 1024 * NI;  // 31,457,280

DEVINL ushort f2bf(float x) {   // round-to-nearest-even fp32 -> bf16 bits
  unsigned u = __float_as_uint(x);
  u += 0x7FFFu + ((u >> 16) & 1u);
  return (ushort)(u >> 16);
}
DEVINL float bf2f(ushort v) { return __uint_as_float((unsigned)v << 16); }

// ---- fused prep+xpose: blocks [0,4096) transpose x -> tiled xt; blocks
// [4096, 4096+1792) convert W -> wb[((m*32+k/8)*256+o)*8+k%8].
// xt tiling (R17-verified): (c,b,k) at c*CPLANE + (b>>5)*8192 + (k>>6)*2048
// + (b&31)*64 + (k&63); 4 KB GEMM stage tiles contiguous, 128 B write runs.
__global__ __launch_bounds__(256) void prep_xpose(const float* __restrict__ x,
                                                  const float* __restrict__ w0,
                                                  const float* __restrict__ w1,
                                                  const float* __restrict__ w2,
                                                  ushort* __restrict__ xt,
                                                  ushort* __restrict__ wb) {
  __shared__ float tl[64 * 121];       // 31 KB (xpose path only)
  const int bid = blockIdx.x;
  const int t = threadIdx.x;
  if (bid >= 4096) {                   // ---- prep path (1792 blocks)
    const int pb = bid - 4096;
    const int m = pb >> 5;             // 0..55
    const int kc = pb & 31;            // k-chunk of 8
    const float* src;
    if (m < 32)      src = w0 + ((size_t)(m * NO + t)) * NI;
    else if (m < 48) src = w1 + ((size_t)((m - 32) * NO + t)) * NI;
    else             src = w2 + ((size_t)((m - 48) * NO + t)) * NI;
    src += kc * 8;
    float4 a = *reinterpret_cast<const float4*>(src);
    float4 b = *reinterpret_cast<const float4*>(src + 4);
    u16x8 p = { f2bf(a.x), f2bf(a.y), f2bf(a.z), f2bf(a.w),
                f2bf(b.x), f2bf(b.y), f2bf(b.z), f2bf(b.w) };
    *reinterpret_cast<u16x8*>(wb + ((size_t)(pb * 256 + t)) * 8) = p;
    return;
  }
  // ---- xpose path (4096 blocks): R14-proven LDS scheme, R17 tiled dst
  const int b = bid >> 2, iq = bid & 3;
  const float* xb = x + (size_t)b * BROW + (size_t)iq * 64 * NC;
#pragma unroll
  for (int j = 0; j < 15; ++j) {       // 7680 f32, float2 coalesced reads
    const int e = (j * 256 + t) * 2;   // even -> c even, no row wrap (c<=118)
    float2 v = *reinterpret_cast<const float2*>(xb + e);
    const int i = e / 120, c = e % 120;
    tl[i * 121 + c] = v.x;
    tl[i * 121 + c + 1] = v.y;
  }
  __syncthreads();
  ushort* dst = xt + (size_t)(b >> 5) * 8192 + (size_t)iq * 2048 + (b & 31) * 64;
#pragma unroll
  for (int q = 0; q < 4; ++q) {        // 960 chunks (120 c x 8 ich), predicated
    const int chunk = q * 256 + t;
    if (chunk < 960) {
      const int c = chunk >> 3, ich = chunk & 7;
      u16x8 p;
#pragma unroll
      for (int k = 0; k < 8; ++k) p[k] = f2bf(tl[(ich * 8 + k) * 121 + c]);
      *reinterpret_cast<u16x8*>(dst + (size_t)c * CPLANE + ich * 8) = p;
    }
  }
}

// ---- pass 2 (FUSED GEMM, R17 body + ct-FASTEST grid): block = 8c x 64b x 64o,
// 8 waves, wave w owns c = c0+w (one wave-uniform matrix). ct,ct+1 adjacent
// bids -> out-line co-writers temporally adjacent -> partial 32B writes merge
// (R5-proven). W rides L3 (7.3 MB full set per XCD -- accepted, overlapped).
__global__ __launch_bounds__(512, 4) void e3mixD(const ushort* __restrict__ xt,
                                                 const ushort* __restrict__ wb,
                                                 const float* __restrict__ bias0,
                                                 float* __restrict__ out) {
  __shared__ ushort xs[32768];         // 64 KB: staging dbuf 2x32KB; epilogue reuse
  const int bid = blockIdx.x;          // 960: ct FASTEST, oq next, bt slowest
  const int ct = bid % 15;
  const int oq = (bid / 15) & 3;
  const int bt = bid / 60;
  const int c0 = ct * 8, bg = bt * 64, og = oq * 64;

  const int tid = threadIdx.x, lane = tid & 63, w = tid >> 6;   // 8 waves
  const int rb = lane & 15, rg = lane >> 4;
  const int c = c0 + w;                // wave's column; all 120 covered, no tail
  const int m = c < 32 ? c : (c < 80 ? 32 + (c - 32) / 3 : 48 + (c - 80) / 5);

  // staging source: instr j covers rows r = j*8 + lr; kc = (lane&7)^lr is
  // j/bh/s-invariant. LDS dest linear (HW rule).
  const int lr = lane >> 3;
  const ushort* gbase = xt + (size_t)c * CPLANE + (size_t)bt * 16384
                           + lr * 64 + ((lane & 7) ^ lr) * 8;

  f32x4 acc[4][4];                     // [bh*2+fb][fo]
#pragma unroll
  for (int i = 0; i < 4; ++i)
#pragma unroll
    for (int j = 0; j < 4; ++j) acc[i][j] = (f32x4)0.0f;

#define STAGEC(BUF, G)                                                         \
  do {                                                                         \
    const ushort* gs_ = gbase + ((G) >> 2) * 8192 + ((G) & 3) * 2048;          \
    ushort* ld_ = xs + (BUF) * 16384 + w * 2048;                               \
    __builtin_amdgcn_global_load_lds((const AS1 void*)(gs_),        (AS3 void*)(ld_),        16, 0, 0); \
    __builtin_amdgcn_global_load_lds((const AS1 void*)(gs_ + 512),  (AS3 void*)(ld_ + 512),  16, 0, 0); \
    __builtin_amdgcn_global_load_lds((const AS1 void*)(gs_ + 1024), (AS3 void*)(ld_ + 1024), 16, 0, 0); \
    __builtin_amdgcn_global_load_lds((const AS1 void*)(gs_ + 1536), (AS3 void*)(ld_ + 1536), 16, 0, 0); \
  } while (0)

  STAGEC(0, 0);
  __syncthreads();                     // phase 0 staged

#pragma unroll
  for (int g = 0; g < 8; ++g) {        // full unroll: acc indices static
    if (g < 7) STAGEC((g + 1) & 1, g + 1);      // prefetch next phase
    const int bh = g >> 2, s = g & 3;
    const ushort* p = xs + (g & 1) * 16384 + w * 2048;   // wave's [32 b][64 k]
#pragma unroll
    for (int kh = 0; kh < 2; ++kh) {   // two k-halves of 32
      bf16x8 a[2], wf[4];
#pragma unroll
      for (int fb = 0; fb < 2; ++fb)   // A frags: proven swizzle, conflict-free
        a[fb] = *reinterpret_cast<const bf16x8*>(
            p + (fb * 16 + rb) * 64 + (((kh * 4 + rg) ^ (rb & 7)) * 8));
#pragma unroll
      for (int fo = 0; fo < 4; ++fo)   // W frags: 256B-coalesced
        wf[fo] = *reinterpret_cast<const bf16x8*>(
            wb + ((size_t)((m * 32 + s * 8 + kh * 4 + rg) * NO
                           + og + fo * 16 + rb)) * 8);
#pragma unroll
      for (int fb = 0; fb < 2; ++fb)
#pragma unroll
        for (int fo = 0; fo < 4; ++fo)
          acc[bh * 2 + fb][fo] = __builtin_amdgcn_mfma_f32_16x16x32_bf16(
              a[fb], wf[fo], acc[bh * 2 + fb][fo], 0, 0, 0);
    }
    __syncthreads();                   // drains prefetch; protects buf reuse
  }
#undef STAGEC

  if (ct < 4) {                        // c0 < 32: l=0 irreps carry bias b0[c][o]
#pragma unroll
    for (int fo = 0; fo < 4; ++fo) {
      const float bv = bias0[c * NO + og + fo * 16 + rb];
#pragma unroll
      for (int i = 0; i < 4; ++i) acc[i][fo] += bv;
    }
  }

  // epilogue (R17-verified): per b-half, repack [32 b'][64 o][8 c] bf16
  // (stride 520) -> 32B-contiguous f32 stores.
#pragma unroll 1
  for (int h = 0; h < 2; ++h) {
    if (h) __syncthreads();            // previous half's reads done
#pragma unroll
    for (int fb = 0; fb < 2; ++fb)
#pragma unroll
      for (int r = 0; r < 4; ++r)
#pragma unroll
        for (int fo = 0; fo < 4; ++fo)
          xs[(fb * 16 + rg * 4 + r) * 520 + (fo * 16 + rb) * 8 + w] =
              f2bf(acc[h * 2 + fb][fo][r]);
    __syncthreads();
#pragma unroll
    for (int i = 0; i < 4; ++i) {      // 2048 (b,o) groups per half, 4/thread
      const int g = i * 512 + tid;
      const int bp = g >> 6, o = g & 63;
      u16x8 v = *reinterpret_cast<const u16x8*>(xs + bp * 520 + o * 8);
      float4 lo = make_float4(bf2f(v[0]), bf2f(v[1]), bf2f(v[2]), bf2f(v[3]));
      float4 hi = make_float4(bf2f(v[4]), bf2f(v[5]), bf2f(v[6]), bf2f(v[7]));
      float* dst = out + ((size_t)(bg + h * 32 + bp) * NO + og + o) * NC + c0;
      *reinterpret_cast<float4*>(dst) = lo;     // 32B contiguous, 32B-aligned
      *reinterpret_cast<float4*>(dst + 4) = hi;
    }
  }
}

// ---- fallback (small ws): direct strided gather from x, validated in R5 ----
__global__ __launch_bounds__(512, 4) void e3mix2f(const float* __restrict__ x,
                                                  const ushort* __restrict__ wb,
                                                  const float* __restrict__ bias0,
                                                  float* __restrict__ out) {
  __shared__ ushort xs[8 * 16 * 64];
  const int bid = blockIdx.x;          // 960 = 15 ct * 64 bt
  const int ct = bid % 15, bt = bid / 15;
  const int c0 = ct * 8, bg = bt * 16;
  const int t = threadIdx.x, lane = t & 63, wid = t >> 6;
  const int sb = lane >> 2, sp = lane & 3;
  const int rb = lane & 15, rg = lane >> 4;
  const int oc = wid * 16 + rb;
  const int srow = (wid * 16 + sb) * 64;
  const int sk0 = (sp * 16) ^ ((sb & 7) << 3);
  const int sk1 = (sp * 16 + 8) ^ ((sb & 7) << 3);

  f32x4 acc[8][2];
#pragma unroll
  for (int i = 0; i < 8; ++i) { acc[i][0] = (f32x4)0.0f; acc[i][1] = (f32x4)0.0f; }
  bf16x8 w00 = {}, w01 = {}, w10 = {}, w11 = {};

#pragma unroll 1
  for (int s = 0; s < 4; ++s) {
    if (s) __syncthreads();
    u16x8 v0, v1;
    const float* src = x + (size_t)(bg + sb) * (NI * NC)
                         + (size_t)(s * 64 + sp * 16) * NC + (c0 + wid);
#pragma unroll
    for (int jj = 0; jj < 8; ++jj) v0[jj] = f2bf(src[jj * NC]);
#pragma unroll
    for (int jj = 0; jj < 8; ++jj) v1[jj] = f2bf(src[(8 + jj) * NC]);
    *reinterpret_cast<u16x8*>(&xs[srow + sk0]) = v0;
    *reinterpret_cast<u16x8*>(&xs[srow + sk1]) = v1;
    __syncthreads();

    int mprev = -1;
#pragma unroll
    for (int cc = 0; cc < 8; ++cc) {
      const int c = c0 + cc;
      const int m = c < 32 ? c : (c < 80 ? 32 + (c - 32) / 3 : 48 + (c - 80) / 5);
      if (m != mprev) {
        const ushort* wp = wb + ((size_t)((m * 32 + s * 8 + rg) * NO + oc)) * 8;
        w00 = *reinterpret_cast<const bf16x8*>(wp);
        w10 = *reinterpret_cast<const bf16x8*>(wp + (size_t)4 * NO * 8);
        w01 = *reinterpret_cast<const bf16x8*>(wp + 128 * 8);
        w11 = *reinterpret_cast<const bf16x8*>(wp + (size_t)4 * NO * 8 + 128 * 8);
        mprev = m;
      }
      const ushort* xp = xs + (cc * 16 + rb) * 64;
      const int sz = (rb & 7) << 3;
      bf16x8 a0 = *reinterpret_cast<const bf16x8*>(xp + ((rg * 8) ^ sz));
      bf16x8 a1 = *reinterpret_cast<const bf16x8*>(xp + ((32 + rg * 8) ^ sz));
      acc[cc][0] = __builtin_amdgcn_mfma_f32_16x16x32_bf16(a0, w00, acc[cc][0], 0, 0, 0);
      acc[cc][0] = __builtin_amdgcn_mfma_f32_16x16x32_bf16(a1, w10, acc[cc][0], 0, 0, 0);
      acc[cc][1] = __builtin_amdgcn_mfma_f32_16x16x32_bf16(a0, w01, acc[cc][1], 0, 0, 0);
      acc[cc][1] = __builtin_amdgcn_mfma_f32_16x16x32_bf16(a1, w11, acc[cc][1], 0, 0, 0);
    }
  }

  if (c0 < 32) {
#pragma unroll
    for (int cc = 0; cc < 8; ++cc) {
      acc[cc][0] += bias0[(c0 + cc) * NO + oc];
      acc[cc][1] += bias0[(c0 + cc) * NO + oc + 128];
    }
  }

  const int br0 = bg + rg * 4;
#pragma unroll
  for (int of = 0; of < 2; ++of)
#pragma unroll
    for (int r = 0; r < 4; ++r) {
      float4 va = make_float4(acc[0][of][r], acc[1][of][r], acc[2][of][r], acc[3][of][r]);
      float4 vb = make_float4(acc[4][of][r], acc[5][of][r], acc[6][of][r], acc[7][of][r]);
      float* dst = out + ((size_t)(br0 + r) * NO + oc + of * 128) * NC + c0;
      *reinterpret_cast<float4*>(dst) = va;
      *reinterpret_cast<float4*>(dst + 4) = vb;
    }
}

extern "C" void kernel_launch(void* const* d_in, const int* in_sizes, int n_in,
                              void* d_out, int out_size, void* d_ws, size_t ws_size,
                              hipStream_t stream) {
  const float* x  = (const float*)d_in[0];
  const float* w0 = (const float*)d_in[1];
  const float* w1 = (const float*)d_in[2];
  const float* w2 = (const float*)d_in[3];
  const float* b0 = (const float*)d_in[4];
  float* out = (float*)d_out;
  ushort* wb = (ushort*)d_ws;                       // 7.34 MB
  ushort* xt = wb + WELEMS;                         // +62.9 MB (tiled)

  const bool big = ws_size >= (size_t)2 * (WELEMS + XT_ELEMS);
  if (big) {
    prep_xpose<<<4096 + 1792, 256, 0, stream>>>(x, w0, w1, w2, xt, wb);
    e3mixD<<<960, 512, 0, stream>>>(xt, wb, b0, out);
  } else {
    // fallback needs wb only
    prep_xpose<<<4096 + 1792, 256, 0, stream>>>(x, w0, w1, w2, xt, wb);  // xt unused writes ok? no -- guard below
    e3mix2f<<<960, 512, 0, stream>>>(x, wb, b0, out);
  }
}

// Round 19
// 285.585 us; speedup vs baseline: 1.0464x; 1.0286x over previous
//
#include <hip/hip_runtime.h>

typedef __attribute__((ext_vector_type(8))) short bf16x8;
typedef __attribute__((ext_vector_type(4))) float f32x4;
typedef __attribute__((ext_vector_type(8))) unsigned short u16x8;

#define DEVINL __device__ __forceinline__
#define AS1 __attribute__((address_space(1)))
#define AS3 __attribute__((address_space(3)))

constexpr int NI = 256;   // input channels (K)
constexpr int NO = 256;   // output channels
constexpr int NC = 120;   // irrep feature width
constexpr int BROW = NC * NI;                        // 30720 f32 per b of x
constexpr int CPLANE = 1024 * NI;                    // 262144: one c-plane of xt
constexpr int WELEMS = 56 * NO * NI;                 // 3,670,016
constexpr size_t XT_ELEMS = (size_t)NC * 1024 * NI;  // 31,457,280

DEVINL ushort f2bf(float x) {   // round-to-nearest-even fp32 -> bf16 bits
  unsigned u = __float_as_uint(x);
  u += 0x7FFFu + ((u >> 16) & 1u);
  return (ushort)(u >> 16);
}
DEVINL float bf2f(ushort v) { return __uint_as_float((unsigned)v << 16); }

// ---- fused prep+xpose. Blocks [0,xblocks): transpose x -> tiled xt (R17
// layout: (c,b,k) at c*CPLANE + (b>>5)*8192 + (k>>6)*2048 + (b&31)*64 + (k&63)).
// Blocks [xblocks, ...): W -> wb[((m*32+k/8)*256+o)*8+k%8]. xblocks=0 in
// small-ws mode so xt is never touched (R18 bug fixed).
__global__ __launch_bounds__(256) void prep_xpose(const float* __restrict__ x,
                                                  const float* __restrict__ w0,
                                                  const float* __restrict__ w1,
                                                  const float* __restrict__ w2,
                                                  ushort* __restrict__ xt,
                                                  ushort* __restrict__ wb,
                                                  int xblocks) {
  __shared__ float tl[64 * 121];       // 31 KB (xpose path only)
  const int bid = blockIdx.x;
  const int t = threadIdx.x;
  if (bid >= xblocks) {                // ---- prep path (1792 blocks)
    const int pb = bid - xblocks;
    const int m = pb >> 5;             // 0..55
    const int kc = pb & 31;            // k-chunk of 8
    const float* src;
    if (m < 32)      src = w0 + ((size_t)(m * NO + t)) * NI;
    else if (m < 48) src = w1 + ((size_t)((m - 32) * NO + t)) * NI;
    else             src = w2 + ((size_t)((m - 48) * NO + t)) * NI;
    src += kc * 8;
    float4 a = *reinterpret_cast<const float4*>(src);
    float4 b = *reinterpret_cast<const float4*>(src + 4);
    u16x8 p = { f2bf(a.x), f2bf(a.y), f2bf(a.z), f2bf(a.w),
                f2bf(b.x), f2bf(b.y), f2bf(b.z), f2bf(b.w) };
    *reinterpret_cast<u16x8*>(wb + ((size_t)(pb * 256 + t)) * 8) = p;
    return;
  }
  // ---- xpose path: R14-proven LDS scheme, R17 tiled dst
  const int b = bid >> 2, iq = bid & 3;
  const float* xb = x + (size_t)b * BROW + (size_t)iq * 64 * NC;
#pragma unroll
  for (int j = 0; j < 15; ++j) {       // 7680 f32, float2 coalesced reads
    const int e = (j * 256 + t) * 2;   // even -> c even, no row wrap (c<=118)
    float2 v = *reinterpret_cast<const float2*>(xb + e);
    const int i = e / 120, c = e % 120;
    tl[i * 121 + c] = v.x;
    tl[i * 121 + c + 1] = v.y;
  }
  __syncthreads();
  ushort* dst = xt + (size_t)(b >> 5) * 8192 + (size_t)iq * 2048 + (b & 31) * 64;
#pragma unroll
  for (int q = 0; q < 4; ++q) {        // 960 chunks (120 c x 8 ich), predicated
    const int chunk = q * 256 + t;
    if (chunk < 960) {
      const int c = chunk >> 3, ich = chunk & 7;
      u16x8 p;
#pragma unroll
      for (int k = 0; k < 8; ++k) p[k] = f2bf(tl[(ich * 8 + k) * 121 + c]);
      *reinterpret_cast<u16x8*>(dst + (size_t)c * CPLANE + ich * 8) = p;
    }
  }
}

// ---- FUSED GEMM (R18 body, spill-free): block = 8c x 64b x 32o, 8 waves.
// Wave w owns c = c0+w (one wave-uniform matrix). acc = 32 AGPR -> total
// regs ~87 << 128 cap of (512,4): NO scratch spill (R17/R18's 6.4x WRITE).
// K=256 as 2 b-halves x 4 K-stages of 64; tiled-xt staging (2 KB contiguous
// per wave per phase). Epilogue: repack [32 b'][32 o][8 c] -> 32B f32 runs.
__global__ __launch_bounds__(512, 4) void e3mixE(const ushort* __restrict__ xt,
                                                 const ushort* __restrict__ wb,
                                                 const float* __restrict__ bias0,
                                                 float* __restrict__ out) {
  __shared__ ushort xs[32768];         // 64 KB: staging dbuf 2x32KB; epilogue reuse
  const int bid = blockIdx.x;          // 1920: ct FASTEST, oq next, bt slowest
  const int ct = bid % 15;
  const int oq = (bid / 15) & 7;       // 8 oq-sharers of xt slice are bid-near
  const int bt = bid / 120;
  const int c0 = ct * 8, bg = bt * 64, og = oq * 32;

  const int tid = threadIdx.x, lane = tid & 63, w = tid >> 6;   // 8 waves
  const int rb = lane & 15, rg = lane >> 4;
  const int c = c0 + w;                // wave's column; all 120 covered, no tail
  const int m = c < 32 ? c : (c < 80 ? 32 + (c - 32) / 3 : 48 + (c - 80) / 5);

  // staging source: instr j covers rows r = j*8 + lr of the [32 b][64 k] tile;
  // global chunk = (lane&7) ^ lr (involution, row&7 == lr). LDS dest linear.
  const int lr = lane >> 3;
  const ushort* gbase = xt + (size_t)c * CPLANE + (size_t)bt * 16384
                           + lr * 64 + ((lane & 7) ^ lr) * 8;

  f32x4 acc[4][2];                     // [bh*2+fb][fo]: 32 regs (AGPR)
#pragma unroll
  for (int i = 0; i < 4; ++i) {
    acc[i][0] = (f32x4)0.0f;
    acc[i][1] = (f32x4)0.0f;
  }

#define STAGEE(BUF, G)                                                         \
  do {                                                                         \
    const ushort* gs_ = gbase + ((G) >> 2) * 8192 + ((G) & 3) * 2048;          \
    ushort* ld_ = xs + (BUF) * 16384 + w * 2048;                               \
    __builtin_amdgcn_global_load_lds((const AS1 void*)(gs_),        (AS3 void*)(ld_),        16, 0, 0); \
    __builtin_amdgcn_global_load_lds((const AS1 void*)(gs_ + 512),  (AS3 void*)(ld_ + 512),  16, 0, 0); \
    __builtin_amdgcn_global_load_lds((const AS1 void*)(gs_ + 1024), (AS3 void*)(ld_ + 1024), 16, 0, 0); \
    __builtin_amdgcn_global_load_lds((const AS1 void*)(gs_ + 1536), (AS3 void*)(ld_ + 1536), 16, 0, 0); \
  } while (0)

  STAGEE(0, 0);
  __syncthreads();                     // phase 0 staged

#pragma unroll
  for (int g = 0; g < 8; ++g) {        // full unroll: acc indices static
    if (g < 7) STAGEE((g + 1) & 1, g + 1);      // prefetch next phase
    const int bh = g >> 2, s = g & 3;
    const ushort* p = xs + (g & 1) * 16384 + w * 2048;   // wave's [32 b][64 k]
#pragma unroll
    for (int kh = 0; kh < 2; ++kh) {   // two k-halves of 32
      bf16x8 a[2], wf[2];
#pragma unroll
      for (int fb = 0; fb < 2; ++fb)   // A frags: proven swizzle
        a[fb] = *reinterpret_cast<const bf16x8*>(
            p + (fb * 16 + rb) * 64 + (((kh * 4 + rg) ^ (rb & 7)) * 8));
#pragma unroll
      for (int fo = 0; fo < 2; ++fo)   // W frags: 256B-coalesced
        wf[fo] = *reinterpret_cast<const bf16x8*>(
            wb + ((size_t)((m * 32 + s * 8 + kh * 4 + rg) * NO
                           + og + fo * 16 + rb)) * 8);
#pragma unroll
      for (int fb = 0; fb < 2; ++fb)
#pragma unroll
        for (int fo = 0; fo < 2; ++fo)
          acc[bh * 2 + fb][fo] = __builtin_amdgcn_mfma_f32_16x16x32_bf16(
              a[fb], wf[fo], acc[bh * 2 + fb][fo], 0, 0, 0);
    }
    __syncthreads();                   // drains prefetch; protects buf reuse
  }
#undef STAGEE

  if (ct < 4) {                        // c0 < 32: l=0 irreps carry bias b0[c][o]
#pragma unroll
    for (int fo = 0; fo < 2; ++fo) {
      const float bv = bias0[c * NO + og + fo * 16 + rb];
#pragma unroll
      for (int i = 0; i < 4; ++i) acc[i][fo] += bv;
    }
  }

  // epilogue: per b-half, repack [32 b'][32 o][8 c] bf16 (row stride 264)
  // -> 32B-contiguous f32 stores (clean class when unspilled: R13/R14).
#pragma unroll 1
  for (int h = 0; h < 2; ++h) {
    if (h) __syncthreads();            // previous half's reads done
#pragma unroll
    for (int fb = 0; fb < 2; ++fb)
#pragma unroll
      for (int r = 0; r < 4; ++r)
#pragma unroll
        for (int fo = 0; fo < 2; ++fo)
          xs[(fb * 16 + rg * 4 + r) * 264 + (fo * 16 + rb) * 8 + w] =
              f2bf(acc[h * 2 + fb][fo][r]);
    __syncthreads();
#pragma unroll
    for (int i = 0; i < 2; ++i) {      // 1024 (b,o) groups per half, 2/thread
      const int g = i * 512 + tid;
      const int bp = g >> 5, o = g & 31;
      u16x8 v = *reinterpret_cast<const u16x8*>(xs + bp * 264 + o * 8);
      float4 lo = make_float4(bf2f(v[0]), bf2f(v[1]), bf2f(v[2]), bf2f(v[3]));
      float4 hi = make_float4(bf2f(v[4]), bf2f(v[5]), bf2f(v[6]), bf2f(v[7]));
      float* dst = out + ((size_t)(bg + h * 32 + bp) * NO + og + o) * NC + c0;
      *reinterpret_cast<float4*>(dst) = lo;     // 32B contiguous, 32B-aligned
      *reinterpret_cast<float4*>(dst + 4) = hi;
    }
  }
}

// ---- fallback (small ws): direct strided gather from x, validated in R5 ----
__global__ __launch_bounds__(512, 4) void e3mix2f(const float* __restrict__ x,
                                                  const ushort* __restrict__ wb,
                                                  const float* __restrict__ bias0,
                                                  float* __restrict__ out) {
  __shared__ ushort xs[8 * 16 * 64];
  const int bid = blockIdx.x;          // 960 = 15 ct * 64 bt
  const int ct = bid % 15, bt = bid / 15;
  const int c0 = ct * 8, bg = bt * 16;
  const int t = threadIdx.x, lane = t & 63, wid = t >> 6;
  const int sb = lane >> 2, sp = lane & 3;
  const int rb = lane & 15, rg = lane >> 4;
  const int oc = wid * 16 + rb;
  const int srow = (wid * 16 + sb) * 64;
  const int sk0 = (sp * 16) ^ ((sb & 7) << 3);
  const int sk1 = (sp * 16 + 8) ^ ((sb & 7) << 3);

  f32x4 acc[8][2];
#pragma unroll
  for (int i = 0; i < 8; ++i) { acc[i][0] = (f32x4)0.0f; acc[i][1] = (f32x4)0.0f; }
  bf16x8 w00 = {}, w01 = {}, w10 = {}, w11 = {};

#pragma unroll 1
  for (int s = 0; s < 4; ++s) {
    if (s) __syncthreads();
    u16x8 v0, v1;
    const float* src = x + (size_t)(bg + sb) * (NI * NC)
                         + (size_t)(s * 64 + sp * 16) * NC + (c0 + wid);
#pragma unroll
    for (int jj = 0; jj < 8; ++jj) v0[jj] = f2bf(src[jj * NC]);
#pragma unroll
    for (int jj = 0; jj < 8; ++jj) v1[jj] = f2bf(src[(8 + jj) * NC]);
    *reinterpret_cast<u16x8*>(&xs[srow + sk0]) = v0;
    *reinterpret_cast<u16x8*>(&xs[srow + sk1]) = v1;
    __syncthreads();

    int mprev = -1;
#pragma unroll
    for (int cc = 0; cc < 8; ++cc) {
      const int c = c0 + cc;
      const int m = c < 32 ? c : (c < 80 ? 32 + (c - 32) / 3 : 48 + (c - 80) / 5);
      if (m != mprev) {
        const ushort* wp = wb + ((size_t)((m * 32 + s * 8 + rg) * NO + oc)) * 8;
        w00 = *reinterpret_cast<const bf16x8*>(wp);
        w10 = *reinterpret_cast<const bf16x8*>(wp + (size_t)4 * NO * 8);
        w01 = *reinterpret_cast<const bf16x8*>(wp + 128 * 8);
        w11 = *reinterpret_cast<const bf16x8*>(wp + (size_t)4 * NO * 8 + 128 * 8);
        mprev = m;
      }
      const ushort* xp = xs + (cc * 16 + rb) * 64;
      const int sz = (rb & 7) << 3;
      bf16x8 a0 = *reinterpret_cast<const bf16x8*>(xp + ((rg * 8) ^ sz));
      bf16x8 a1 = *reinterpret_cast<const bf16x8*>(xp + ((32 + rg * 8) ^ sz));
      acc[cc][0] = __builtin_amdgcn_mfma_f32_16x16x32_bf16(a0, w00, acc[cc][0], 0, 0, 0);
      acc[cc][0] = __builtin_amdgcn_mfma_f32_16x16x32_bf16(a1, w10, acc[cc][0], 0, 0, 0);
      acc[cc][1] = __builtin_amdgcn_mfma_f32_16x16x32_bf16(a0, w01, acc[cc][1], 0, 0, 0);
      acc[cc][1] = __builtin_amdgcn_mfma_f32_16x16x32_bf16(a1, w11, acc[cc][1], 0, 0, 0);
    }
  }

  if (c0 < 32) {
#pragma unroll
    for (int cc = 0; cc < 8; ++cc) {
      acc[cc][0] += bias0[(c0 + cc) * NO + oc];
      acc[cc][1] += bias0[(c0 + cc) * NO + oc + 128];
    }
  }

  const int br0 = bg + rg * 4;
#pragma unroll
  for (int of = 0; of < 2; ++of)
#pragma unroll
    for (int r = 0; r < 4; ++r) {
      float4 va = make_float4(acc[0][of][r], acc[1][of][r], acc[2][of][r], acc[3][of][r]);
      float4 vb = make_float4(acc[4][of][r], acc[5][of][r], acc[6][of][r], acc[7][of][r]);
      float* dst = out + ((size_t)(br0 + r) * NO + oc + of * 128) * NC + c0;
      *reinterpret_cast<float4*>(dst) = va;
      *reinterpret_cast<float4*>(dst + 4) = vb;
    }
}

extern "C" void kernel_launch(void* const* d_in, const int* in_sizes, int n_in,
                              void* d_out, int out_size, void* d_ws, size_t ws_size,
                              hipStream_t stream) {
  const float* x  = (const float*)d_in[0];
  const float* w0 = (const float*)d_in[1];
  const float* w1 = (const float*)d_in[2];
  const float* w2 = (const float*)d_in[3];
  const float* b0 = (const float*)d_in[4];
  float* out = (float*)d_out;
  ushort* wb = (ushort*)d_ws;                       // 7.34 MB
  ushort* xt = wb + WELEMS;                         // +62.9 MB (tiled)

  const bool big = ws_size >= (size_t)2 * (WELEMS + XT_ELEMS);
  if (big) {
    prep_xpose<<<4096 + 1792, 256, 0, stream>>>(x, w0, w1, w2, xt, wb, 4096);
    e3mixE<<<1920, 512, 0, stream>>>(xt, wb, b0, out);
  } else {
    prep_xpose<<<1792, 256, 0, stream>>>(x, w0, w1, w2, nullptr, wb, 0);
    e3mix2f<<<960, 512, 0, stream>>>(x, wb, b0, out);
  }
}